// Round 4
// baseline (611.895 us; speedup 1.0000x reference)
//
#include <hip/hip_runtime.h>

typedef __attribute__((ext_vector_type(8))) short short8;
typedef __attribute__((ext_vector_type(4))) int int4v;
typedef __attribute__((ext_vector_type(4))) float floatx4;
typedef __attribute__((ext_vector_type(4))) unsigned int uintx4;

__device__ __forceinline__ short f2bf(float f) {
    unsigned u = __builtin_bit_cast(unsigned, f);
    u = (u + 0x7FFFu + ((u >> 16) & 1u)) >> 16;
    return (short)u;
}

// ---------------------------------------------------------------------------
// Workspace layout (ushort element offsets):
//   w1T0=0, w1T1=65536, w1T2=196608, w2T0=458752, w2T1=524288, w2T2=589824
//   xg0=655360 (4096x256), xg1=1703936 (4096x512), xg2=3801088 (4096x1024)
//   LUTG=7995392: int32 LUTs, lut0g[16384], lut1g[4096], lut2g[1024]
//   total 16.08 MB
// ---------------------------------------------------------------------------
#define W1T0 0
#define W1T1 65536
#define W1T2 196608
#define W2T0 458752
#define W2T1 524288
#define W2T2 589824
#define XG0  655360
#define XG1  1703936
#define XG2  3801088
#define LUTG 7995392

// ---------------------------------------------------------------------------
// stage (single launch, 1921 blocks):
//  [0,512):    scan feat0  (16 b x 8 chgrp x 4 hwseg; 512KB reads each)
//  [512,768):  scan feat1  (16 b x 16 chgrp;          512KB reads each)
//  [768,1280): scan feat2  (16 b x 32 chgrp;          128KB reads each)
//  [1280,1920): weight transpose+bf16 (fp32 w[K][256] -> bf16 wT[256][K])
//  1920:       global int32 LUT build (atomicMax winner — deterministic,
//              matches the per-block LDS LUT winner for duplicate pids)
// Scan: fully streamed coalesced float4 reads of the feature tensor; match
// positions against a per-block LDS LUT (atomicMax scatter of the 256 pids
// restricted to this block's hw window); collect matched elements in an LDS
// tile [256 patch][40-stride ch]; write matched rows as aligned 64B chunks.
// LDS: lut 4096 int (16KB) + tile 256x40 us (20KB) + flags 1KB = 37.9KB.
// ---------------------------------------------------------------------------
__global__ __launch_bounds__(256) void stage(
    const float* __restrict__ f0, const float* __restrict__ f1, const float* __restrict__ f2,
    const int* __restrict__ p0, const int* __restrict__ p1, const int* __restrict__ p2,
    const float* __restrict__ w10, const float* __restrict__ w11, const float* __restrict__ w12,
    const float* __restrict__ w20, const float* __restrict__ w21, const float* __restrict__ w22,
    unsigned short* __restrict__ wsb)
{
    __shared__ __align__(16) unsigned char smemraw[37888];
    int blk = blockIdx.x;
    int t = threadIdx.x;

    if (blk >= 1280) {
        if (blk == 1920) {
            // global LUT: init -1 then atomicMax scatter
            int* lutg = (int*)(wsb + LUTG);
            for (int i = t; i < 21504; i += 256) lutg[i] = -1;
            __syncthreads();
            atomicMax(&lutg[p0[t]], t);
            atomicMax(&lutg[16384 + p1[t]], t);
            atomicMax(&lutg[20480 + p2[t]], t);
            return;
        }
        // weight transpose
        float (*tileF)[33] = (float(*)[33])smemraw;
        int b2 = blk - 1280;
        const float* in; unsigned short* out; int K, t0;
        if (b2 < 64)       { in = w10; out = wsb + W1T0; K = 256;  t0 = 0; }
        else if (b2 < 192) { in = w11; out = wsb + W1T1; K = 512;  t0 = 64; }
        else if (b2 < 448) { in = w12; out = wsb + W1T2; K = 1024; t0 = 192; }
        else if (b2 < 512) { in = w20; out = wsb + W2T0; K = 256;  t0 = 448; }
        else if (b2 < 576) { in = w21; out = wsb + W2T1; K = 256;  t0 = 512; }
        else               { in = w22; out = wsb + W2T2; K = 256;  t0 = 576; }
        int tile_id = b2 - t0;
        int tk = K >> 5;
        int k0 = (tile_id % tk) << 5;
        int n0 = (tile_id / tk) << 5;
        int j = t & 31, i0 = (t >> 5) << 2;
        #pragma unroll
        for (int u = 0; u < 4; u++)
            tileF[i0 + u][j] = in[(size_t)(k0 + i0 + u) * 256 + (n0 + j)];
        __syncthreads();
        int kf = t & 31, nf0 = (t >> 5) << 2;
        #pragma unroll
        for (int u = 0; u < 4; u++)
            out[(size_t)(n0 + nf0 + u) * K + (k0 + kf)] = (unsigned short)f2bf(tileF[kf][nf0 + u]);
        return;
    }

    // ---------------- streamed LUT-scan ----------------
    int* lut = (int*)smemraw;                                   // 4096 ints
    unsigned short* tile = (unsigned short*)(smemraw + 16384);  // 256*40
    int* flags = (int*)(smemraw + 16384 + 20480);               // 256

    const float* feat; const int* pid; unsigned short* xg;
    int C, HW, b, c0, hw0, seg;
    if (blk < 512) {
        feat = f0; pid = p0; xg = wsb + XG0; C = 256; HW = 16384;
        b = blk >> 5; int rem = blk & 31;
        c0 = (rem >> 2) << 5; hw0 = (rem & 3) << 12; seg = 4096;
    } else if (blk < 768) {
        int idx = blk - 512;
        feat = f1; pid = p1; xg = wsb + XG1; C = 512; HW = 4096;
        b = idx >> 4; c0 = (idx & 15) << 5; hw0 = 0; seg = 4096;
    } else {
        int idx = blk - 768;
        feat = f2; pid = p2; xg = wsb + XG2; C = 1024; HW = 1024;
        b = idx >> 5; c0 = (idx & 31) << 5; hw0 = 0; seg = 1024;
    }

    for (int i = t; i < seg; i += 256) lut[i] = -1;
    flags[t] = 0;
    __syncthreads();
    {
        int s = pid[t] - hw0;
        if ((unsigned)s < (unsigned)seg) atomicMax(&lut[s], t);
    }
    __syncthreads();

    int cl = t >> 3, sub = t & 7;                 // 32 channels x 8 subs
    const float* fr = feat + ((size_t)b * C + c0 + cl) * HW + hw0;
    int iters = seg >> 5;
    for (int i = 0; i < iters; i++) {
        int hw = (i << 5) + (sub << 2);
        floatx4 v = *(const floatx4*)(fr + hw);
        int4v l4 = *(const int4v*)(lut + hw);
        #pragma unroll
        for (int j = 0; j < 4; j++) {
            int pv = l4[j];
            if (pv >= 0) {
                tile[pv * 40 + cl] = (unsigned short)f2bf(v[j]);
                flags[pv] = 1;
            }
        }
    }
    __syncthreads();
    if (flags[t]) {
        uintx4* d = (uintx4*)(xg + (size_t)(b * 256 + t) * C + c0);
        const uintx4* s4 = (const uintx4*)(tile + t * 40);
        d[0] = s4[0]; d[1] = s4[1]; d[2] = s4[2]; d[3] = s4[3];
    }
}

// ---------------------------------------------------------------------------
// mlp: 192 blocks (64/scale, scale2 first), 64 rows x 256 cols per block,
// 4 waves (wave w = cols w*64, all 64 rows). 16 fragments/wave -> per k-step:
// 8 frag-loads : 16 MFMAs. A and B read directly from global (L2/IC-hot).
// Weight B-traffic: 192 blocks x (C+256)*128KB ~ 84 MB total (4x less than
// 16-row blocks). A-rows resolved through the global LUT (duplicate pids).
// LDS: hs 64x264 us (33.8KB) + rs 64 f32.
// ---------------------------------------------------------------------------
__global__ __launch_bounds__(256, 2) void mlp(
    const float* __restrict__ b1_0, const float* __restrict__ b1_1, const float* __restrict__ b1_2,
    const float* __restrict__ b2_0, const float* __restrict__ b2_1, const float* __restrict__ b2_2,
    const int* __restrict__ p0, const int* __restrict__ p1, const int* __restrict__ p2,
    const unsigned short* __restrict__ wsb,
    float* __restrict__ out)
{
    __shared__ __align__(16) unsigned short hs[64 * 264];
    __shared__ float rs[64];

    int blk = blockIdx.x;
    int scale = 2 - (blk >> 6);
    int mblk = blk & 63;

    const float *b1, *b2; const int* pid;
    const unsigned short *w1T, *w2T, *xg; const int* lutg;
    int C; size_t outBase;
    const int* lutgB = (const int*)(wsb + LUTG);
    if (scale == 0)      { b1 = b1_0; b2 = b2_0; pid = p0; lutg = lutgB;
                           w1T = wsb + W1T0; w2T = wsb + W2T0; xg = wsb + XG0; C = 256;  outBase = 0; }
    else if (scale == 1) { b1 = b1_1; b2 = b2_1; pid = p1; lutg = lutgB + 16384;
                           w1T = wsb + W1T1; w2T = wsb + W2T1; xg = wsb + XG1; C = 512;  outBase = 1048576; }
    else                 { b1 = b1_2; b2 = b2_2; pid = p2; lutg = lutgB + 20480;
                           w1T = wsb + W1T2; w2T = wsb + W2T2; xg = wsb + XG2; C = 1024; outBase = 2097152; }

    int t = threadIdx.x, wid = t >> 6, lane = t & 63, quad = lane >> 4, l15 = lane & 15;
    int c0 = wid << 6;
    int rowBase = mblk << 6;

    const unsigned short* aB[4];
    #pragma unroll
    for (int rf = 0; rf < 4; rf++) {
        int row = rowBase + rf * 16 + l15;
        int b = row >> 8, pp = row & 255;
        int w = lutg[pid[pp]];
        aB[rf] = xg + (size_t)(b * 256 + w) * C;
    }

    floatx4 acc[4][4];
    #pragma unroll
    for (int rf = 0; rf < 4; rf++)
        #pragma unroll
        for (int cf = 0; cf < 4; cf++) acc[rf][cf] = (floatx4){0.f, 0.f, 0.f, 0.f};

    // ---------------- GEMM1: x[64,C] @ w1[C,256] ----------------
    for (int kc = 0; kc < C; kc += 32) {
        short8 a[4], bv[4];
        #pragma unroll
        for (int rf = 0; rf < 4; rf++)
            a[rf] = *(const short8*)(aB[rf] + kc + quad * 8);
        #pragma unroll
        for (int cf = 0; cf < 4; cf++)
            bv[cf] = *(const short8*)(w1T + (size_t)(c0 + cf * 16 + l15) * C + kc + quad * 8);
        #pragma unroll
        for (int rf = 0; rf < 4; rf++)
            #pragma unroll
            for (int cf = 0; cf < 4; cf++)
                acc[rf][cf] = __builtin_amdgcn_mfma_f32_16x16x32_bf16(a[rf], bv[cf], acc[rf][cf], 0, 0, 0);
    }

    // ---------------- h = relu(acc + b1) -> LDS ----------------
    #pragma unroll
    for (int cf = 0; cf < 4; cf++) {
        float bias = b1[c0 + cf * 16 + l15];
        #pragma unroll
        for (int rf = 0; rf < 4; rf++)
            #pragma unroll
            for (int r = 0; r < 4; r++) {
                float h = fmaxf(acc[rf][cf][r] + bias, 0.f);
                hs[(rf * 16 + quad * 4 + r) * 264 + (c0 + cf * 16 + l15)] = (unsigned short)f2bf(h);
            }
    }
    if (t < 64) rs[t] = 0.f;
    __syncthreads();

    // ---------------- GEMM2: h[64,256] @ w2[256,256] ----------------
    #pragma unroll
    for (int rf = 0; rf < 4; rf++)
        #pragma unroll
        for (int cf = 0; cf < 4; cf++) acc[rf][cf] = (floatx4){0.f, 0.f, 0.f, 0.f};
    for (int kc = 0; kc < 256; kc += 32) {
        short8 a[4], bv[4];
        #pragma unroll
        for (int rf = 0; rf < 4; rf++)
            a[rf] = *(const short8*)(hs + (size_t)(rf * 16 + l15) * 264 + kc + quad * 8);
        #pragma unroll
        for (int cf = 0; cf < 4; cf++)
            bv[cf] = *(const short8*)(w2T + (size_t)(c0 + cf * 16 + l15) * 256 + kc + quad * 8);
        #pragma unroll
        for (int rf = 0; rf < 4; rf++)
            #pragma unroll
            for (int cf = 0; cf < 4; cf++)
                acc[rf][cf] = __builtin_amdgcn_mfma_f32_16x16x32_bf16(a[rf], bv[cf], acc[rf][cf], 0, 0, 0);
    }

    // ---------------- epilogue: y = acc + b2; y / (||y|| + 1e-7) ----------------
    float bias2[4];
    #pragma unroll
    for (int cf = 0; cf < 4; cf++) bias2[cf] = b2[c0 + cf * 16 + l15];
    #pragma unroll
    for (int rf = 0; rf < 4; rf++) {
        float psq[4] = {0.f, 0.f, 0.f, 0.f};
        #pragma unroll
        for (int cf = 0; cf < 4; cf++)
            #pragma unroll
            for (int r = 0; r < 4; r++) {
                float yv = acc[rf][cf][r] + bias2[cf];
                acc[rf][cf][r] = yv;
                psq[r] += yv * yv;
            }
        #pragma unroll
        for (int m = 1; m < 16; m <<= 1)
            #pragma unroll
            for (int r = 0; r < 4; r++)
                psq[r] += __shfl_xor(psq[r], m, 16);
        if (l15 == 0) {
            #pragma unroll
            for (int r = 0; r < 4; r++)
                atomicAdd(&rs[rf * 16 + quad * 4 + r], psq[r]);
        }
    }
    __syncthreads();

    #pragma unroll
    for (int rf = 0; rf < 4; rf++)
        #pragma unroll
        for (int r = 0; r < 4; r++) {
            int row = rf * 16 + quad * 4 + r;
            float inv = 1.f / (sqrtf(rs[row]) + 1e-7f);
            #pragma unroll
            for (int cf = 0; cf < 4; cf++)
                out[outBase + (size_t)(rowBase + row) * 256 + (c0 + cf * 16 + l15)] =
                    acc[rf][cf][r] * inv;
        }
}

extern "C" void kernel_launch(void* const* d_in, const int* in_sizes, int n_in,
                              void* d_out, int out_size, void* d_ws, size_t ws_size,
                              hipStream_t stream)
{
    (void)n_in; (void)out_size; (void)ws_size;
    bool dict = (in_sizes[1] == 256);
    const float *feat[3], *w1[3], *b1[3], *w2[3], *b2[3];
    const int* pid[3];
    for (int i = 0; i < 3; i++) {
        if (dict) {
            feat[i] = (const float*)d_in[i * 6 + 0];
            pid[i]  = (const int*)  d_in[i * 6 + 1];
            w1[i]   = (const float*)d_in[i * 6 + 2];
            b1[i]   = (const float*)d_in[i * 6 + 3];
            w2[i]   = (const float*)d_in[i * 6 + 4];
            b2[i]   = (const float*)d_in[i * 6 + 5];
        } else {
            feat[i] = (const float*)d_in[i];
            pid[i]  = (const int*)  d_in[3 + i];
            w1[i]   = (const float*)d_in[6 + 4 * i + 0];
            b1[i]   = (const float*)d_in[6 + 4 * i + 1];
            w2[i]   = (const float*)d_in[6 + 4 * i + 2];
            b2[i]   = (const float*)d_in[6 + 4 * i + 3];
        }
    }
    unsigned short* wsb = (unsigned short*)d_ws;
    stage<<<1921, 256, 0, stream>>>(feat[0], feat[1], feat[2],
                                    pid[0], pid[1], pid[2],
                                    w1[0], w1[1], w1[2],
                                    w2[0], w2[1], w2[2], wsb);
    mlp<<<192, 256, 0, stream>>>(b1[0], b1[1], b1[2],
                                 b2[0], b2[1], b2[2],
                                 pid[0], pid[1], pid[2],
                                 wsb, (float*)d_out);
}